// Round 4
// baseline (245.774 us; speedup 1.0000x reference)
//
#include <hip/hip_runtime.h>

// SupConLoss on MI355X. features: [4096, 2, 128] fp32; labels: [4096] int; out: 1 f32.
//
// R3 changes vs R2:
//  - k_negsum: LDS-staged A+B tiles (64 KB) via global_load_lds width=16, with
//    XOR chunk swizzle (free on the global side) so ds_read_b128 frag reads are
//    conflict-light. Per-block work 4x R2 (full 128x128 tile from LDS).
//  - negsum is now UNCONDITIONAL row/col exp-sums (allsum) — no labels, no
//    cndmask in the hot loop. neg = allsum - possum reconstructed later.
//  - k_possum (grid 100x4): per-class same-class exp row-sums (incl self) via
//    global atomics. k_loss (grid 100x8): pos-pair log terms.
//
// ws layout: nf (2 MB) | allsum 8192 f32 | possum 8192 f32 | total 1 f32
//            | counts 100 | offsets 101 | classIdx 4096

#define BATCH 4096
#define NN    8192
#define DD    128
#define NCLS  100
#define MAXR  192
#define NB    64
#define NTILE (NB * (NB + 1) / 2)   // 2080
#define SCALE (1.0f / 0.07f)

typedef __attribute__((ext_vector_type(8))) short bf16x8;
typedef __attribute__((ext_vector_type(4))) float f32x4;

__device__ __forceinline__ unsigned short f2bf(float f) {
    unsigned u = __float_as_uint(f);
    u += 0x7FFF + ((u >> 16) & 1);
    return (unsigned short)(u >> 16);
}

__global__ void k_zero(float* p, int n) {
    int i = blockIdx.x * 256 + threadIdx.x;
    if (i < n) p[i] = 0.0f;
}

__global__ void k_normalize(const float* __restrict__ feat, unsigned short* __restrict__ nf) {
    int wave = threadIdx.x >> 6, lane = threadIdx.x & 63;
    int row = blockIdx.x * 4 + wave;
    int v = row >> 12, b = row & (BATCH - 1);
    const float2* src = (const float2*)(feat + ((size_t)b * 2 + v) * DD);
    float2 x = src[lane];
    float ss = x.x * x.x + x.y * x.y;
    #pragma unroll
    for (int m = 32; m >= 1; m >>= 1) ss += __shfl_xor(ss, m, 64);
    float inv = rsqrtf(ss);
    ushort2 o;
    o.x = f2bf(x.x * inv);
    o.y = f2bf(x.y * inv);
    ((ushort2*)(nf + (size_t)row * DD))[lane] = o;
}

__global__ __launch_bounds__(256) void k_bucket(const int* __restrict__ labels,
                                                int* __restrict__ counts,
                                                int* __restrict__ offsets,
                                                int* __restrict__ classIdx) {
    __shared__ int cnt[NCLS], off[NCLS], cur[NCLS];
    int tid = threadIdx.x;
    for (int c = tid; c < NCLS; c += 256) cnt[c] = 0;
    __syncthreads();
    for (int b = tid; b < BATCH; b += 256) atomicAdd(&cnt[labels[b]], 1);
    __syncthreads();
    if (tid == 0) {
        int a = 0;
        for (int c = 0; c < NCLS; ++c) { off[c] = a; a += cnt[c]; }
    }
    __syncthreads();
    for (int c = tid; c < NCLS; c += 256) {
        cur[c] = 0;
        counts[c] = cnt[c];
        offsets[c] = off[c];
    }
    if (tid == 0) offsets[NCLS] = BATCH;
    __syncthreads();
    for (int b = tid; b < BATCH; b += 256) {
        int l = labels[b];
        int p = atomicAdd(&cur[l], 1);
        classIdx[off[l] + p] = b;
    }
}

// ---- pass 1: allsum[i] = sum_j exp(logit_ij), symmetric triangular tiles ----
__global__ __launch_bounds__(256, 2) void k_negsum(
        const unsigned short* __restrict__ nf,
        float* __restrict__ allsum) {
    // 64 KB: 256 combined rows (128 A + 128 B) x 16 swizzled 16B chunks
    __shared__ __attribute__((aligned(16))) unsigned short smem[256 * 128];

    int t = blockIdx.x;
    float ft = (float)t;
    int bi = (int)((2.0f * NB + 1.0f - sqrtf((2.0f * NB + 1.0f) * (2.0f * NB + 1.0f) - 8.0f * ft)) * 0.5f);
    if (bi >= NB) bi = NB - 1;
    while (bi * (2 * NB + 1 - bi) / 2 > t) --bi;
    while ((bi + 1) * (2 * NB - bi) / 2 <= t) ++bi;
    int bj = bi + (t - bi * (2 * NB + 1 - bi) / 2);
    bool diag = (bi == bj);

    int tid = threadIdx.x;
    int wave = tid >> 6, lane = tid & 63;

    // stage: LDS slot (r, cS) holds global chunk (r, cS ^ (r&15)); 1 KB (4 rows) per inst
    #pragma unroll
    for (int it = 0; it < 16; ++it) {
        int chunkIdx = (wave * 16 + it) * 64 + lane;
        int r = chunkIdx >> 4, cS = chunkIdx & 15;
        int cG = cS ^ (r & 15);
        int grow = (r < 128) ? (bi * 128 + r) : (bj * 128 + (r - 128));
        const unsigned short* g = nf + (size_t)grow * DD + cG * 8;
        unsigned short* l = smem + (size_t)(wave * 16 + it) * 512;
        __builtin_amdgcn_global_load_lds(
            (const __attribute__((address_space(1))) void*)g,
            (__attribute__((address_space(3))) void*)l, 16, 0, 0);
    }
    __syncthreads();

    int wr = wave >> 1, wc = wave & 1;
    int q = lane >> 4, nq = lane & 63 & 15;
    const char* sB = (const char*)smem;

    // A frags from LDS (row rA: rA&15 == nq since bases are multiples of 16)
    bf16x8 aF[4][4];
    #pragma unroll
    for (int rs = 0; rs < 4; ++rs) {
        int rA = wr * 64 + rs * 16 + nq;
        #pragma unroll
        for (int s = 0; s < 4; ++s) {
            int slot = rA * 16 + ((s * 4 + q) ^ nq);
            aF[rs][s] = *(const bf16x8*)(sB + slot * 16);
        }
    }
    f32x4 acc[4][4];
    #pragma unroll
    for (int rs = 0; rs < 4; ++rs)
        #pragma unroll
        for (int cs = 0; cs < 4; ++cs) acc[rs][cs] = (f32x4){0.f, 0.f, 0.f, 0.f};
    #pragma unroll
    for (int s = 0; s < 4; ++s) {
        bf16x8 bF[4];
        #pragma unroll
        for (int cs = 0; cs < 4; ++cs) {
            int rB = 128 + wc * 64 + cs * 16 + nq;
            int slot = rB * 16 + ((s * 4 + q) ^ nq);
            bF[cs] = *(const bf16x8*)(sB + slot * 16);
        }
        #pragma unroll
        for (int rs = 0; rs < 4; ++rs)
            #pragma unroll
            for (int cs = 0; cs < 4; ++cs)
                acc[rs][cs] = __builtin_amdgcn_mfma_f32_16x16x32_bf16(
                    aF[rs][s], bF[cs], acc[rs][cs], 0, 0, 0);
    }

    int rowBase = bi * 128 + wr * 64;
    int colBase = bj * 128 + wc * 64;
    float rowsum[4][4];
    #pragma unroll
    for (int rs = 0; rs < 4; ++rs)
        #pragma unroll
        for (int rr = 0; rr < 4; ++rr) rowsum[rs][rr] = 0.0f;

    // C/D layout: col = lane&15, row = (lane>>4)*4 + reg
    #pragma unroll
    for (int cs = 0; cs < 4; ++cs) {
        float colsum = 0.0f;
        #pragma unroll
        for (int rs = 0; rs < 4; ++rs)
            #pragma unroll
            for (int rr = 0; rr < 4; ++rr) {
                float e = __expf(acc[rs][cs][rr] * SCALE);
                rowsum[rs][rr] += e;
                colsum += e;
            }
        if (!diag) {
            colsum += __shfl_xor(colsum, 16, 64);
            colsum += __shfl_xor(colsum, 32, 64);
            if (q == 0) atomicAdd(&allsum[colBase + cs * 16 + nq], colsum);
        }
    }
    #pragma unroll
    for (int rs = 0; rs < 4; ++rs)
        #pragma unroll
        for (int rr = 0; rr < 4; ++rr) {
            float vsum = rowsum[rs][rr];
            vsum += __shfl_xor(vsum, 1, 64);
            vsum += __shfl_xor(vsum, 2, 64);
            vsum += __shfl_xor(vsum, 4, 64);
            vsum += __shfl_xor(vsum, 8, 64);
            if (nq == 0) atomicAdd(&allsum[rowBase + rs * 16 + q * 4 + rr], vsum);
        }
}

// LDS bf16 dot helper for the pair kernels
__device__ __forceinline__ float lds_dot(const unsigned short* s_feat, int p, int qq) {
    float dot = 0.0f;
    #pragma unroll 4
    for (int s = 0; s < 16; ++s) {
        uint4 ua = *(const uint4*)&s_feat[p * 136 + s * 8];
        uint4 ub = *(const uint4*)&s_feat[qq * 136 + s * 8];
        const unsigned* pa = (const unsigned*)&ua;
        const unsigned* pb = (const unsigned*)&ub;
        #pragma unroll
        for (int w = 0; w < 4; ++w) {
            float a0 = __uint_as_float(pa[w] << 16);
            float a1 = __uint_as_float(pa[w] & 0xFFFF0000u);
            float b0 = __uint_as_float(pb[w] << 16);
            float b1 = __uint_as_float(pb[w] & 0xFFFF0000u);
            dot = fmaf(a0, b0, dot);
            dot = fmaf(a1, b1, dot);
        }
    }
    return dot;
}

// possum[row(p)] += exp(logit_pq) over all same-class q INCLUDING q==p (self)
#define PSLICE 4
__global__ __launch_bounds__(256) void k_possum(
        const unsigned short* __restrict__ nf,
        const int* __restrict__ counts, const int* __restrict__ offsets,
        const int* __restrict__ classIdx,
        float* __restrict__ possum) {
    __shared__ int s_rows[MAXR];
    __shared__ __attribute__((aligned(16))) unsigned short s_feat[MAXR * 136];
    int c = blockIdx.x;
    int m = counts[c], off = offsets[c];
    int twoM = 2 * m; if (twoM > MAXR) twoM = MAXR;
    int tid = threadIdx.x;
    for (int r = tid; r < twoM; r += 256) {
        int b = classIdx[off + (r < m ? r : r - m)];
        s_rows[r] = (r < m) ? b : b + BATCH;
    }
    __syncthreads();
    for (int ch = tid; ch < twoM * 16; ch += 256) {
        int r = ch >> 4, s = ch & 15;
        *(uint4*)&s_feat[r * 136 + s * 8] = ((const uint4*)(nf + (size_t)s_rows[r] * DD))[s];
    }
    __syncthreads();
    unsigned P = (unsigned)twoM * (unsigned)twoM;
    for (unsigned t = blockIdx.y * 256 + tid; t < P; t += 256 * PSLICE) {
        unsigned p = t / (unsigned)twoM;
        unsigned qq = t - p * (unsigned)twoM;
        float dot = lds_dot(s_feat, (int)p, (int)qq);
        atomicAdd(&possum[s_rows[p]], __expf(dot * SCALE));
    }
}

// total += sum over pos pairs (p != q) of logit - log(allsum[rq]-possum[rq]+exp(logit))
#define LSLICE 8
__global__ __launch_bounds__(256) void k_loss(
        const unsigned short* __restrict__ nf,
        const int* __restrict__ counts, const int* __restrict__ offsets,
        const int* __restrict__ classIdx,
        const float* __restrict__ allsum, const float* __restrict__ possum,
        float* __restrict__ total) {
    __shared__ int s_rows[MAXR];
    __shared__ __attribute__((aligned(16))) unsigned short s_feat[MAXR * 136];
    int c = blockIdx.x;
    int m = counts[c], off = offsets[c];
    int twoM = 2 * m; if (twoM > MAXR) twoM = MAXR;
    int tid = threadIdx.x;
    for (int r = tid; r < twoM; r += 256) {
        int b = classIdx[off + (r < m ? r : r - m)];
        s_rows[r] = (r < m) ? b : b + BATCH;
    }
    __syncthreads();
    for (int ch = tid; ch < twoM * 16; ch += 256) {
        int r = ch >> 4, s = ch & 15;
        *(uint4*)&s_feat[r * 136 + s * 8] = ((const uint4*)(nf + (size_t)s_rows[r] * DD))[s];
    }
    __syncthreads();
    float partial = 0.0f;
    unsigned P = (unsigned)twoM * (unsigned)twoM;
    for (unsigned t = blockIdx.y * 256 + tid; t < P; t += 256 * LSLICE) {
        unsigned p = t / (unsigned)twoM;
        unsigned qq = t - p * (unsigned)twoM;
        if (p == qq) continue;
        float dot = lds_dot(s_feat, (int)p, (int)qq);
        float logit = dot * SCALE;
        int rq = s_rows[qq];
        float ns = allsum[rq] - possum[rq];
        partial += logit - __logf(ns + __expf(logit));
    }
    #pragma unroll
    for (int mm = 32; mm >= 1; mm >>= 1) partial += __shfl_xor(partial, mm, 64);
    __shared__ float red[4];
    if ((tid & 63) == 0) red[tid >> 6] = partial;
    __syncthreads();
    if (tid == 0) atomicAdd(total, red[0] + red[1] + red[2] + red[3]);
}

__global__ void k_final(const float* __restrict__ total, float* __restrict__ out) {
    out[0] = -total[0] * (1.0f / (float)NN);
}

extern "C" void kernel_launch(void* const* d_in, const int* in_sizes, int n_in,
                              void* d_out, int out_size, void* d_ws, size_t ws_size,
                              hipStream_t stream) {
    const float* feat = (const float*)d_in[0];
    const int* labels = (const int*)d_in[1];
    unsigned short* nf = (unsigned short*)d_ws;
    float* allsum  = (float*)((char*)d_ws + (size_t)NN * DD * sizeof(unsigned short));
    float* possum  = allsum + NN;
    float* total   = possum + NN;           // 1
    int* counts    = (int*)(total + 1);     // 100
    int* offsets   = counts + NCLS;         // 101
    int* classIdx  = offsets + NCLS + 1;    // 4096
    float* out = (float*)d_out;

    int zeroN = 2 * NN + 1;                 // allsum, possum, total (contiguous)
    hipLaunchKernelGGL(k_zero, dim3((zeroN + 255) / 256), dim3(256), 0, stream, allsum, zeroN);
    hipLaunchKernelGGL(k_normalize, dim3(NN / 4), dim3(256), 0, stream, feat, nf);
    hipLaunchKernelGGL(k_bucket, dim3(1), dim3(256), 0, stream, labels, counts, offsets, classIdx);
    hipLaunchKernelGGL(k_negsum, dim3(NTILE), dim3(256), 0, stream, nf, allsum);
    hipLaunchKernelGGL(k_possum, dim3(NCLS, PSLICE), dim3(256), 0, stream,
                       nf, counts, offsets, classIdx, possum);
    hipLaunchKernelGGL(k_loss, dim3(NCLS, LSLICE), dim3(256), 0, stream,
                       nf, counts, offsets, classIdx, allsum, possum, total);
    hipLaunchKernelGGL(k_final, dim3(1), dim3(1), 0, stream, total, out);
}

// Round 5
// 140.125 us; speedup vs baseline: 1.7540x; 1.7540x over previous
//
#include <hip/hip_runtime.h>

// SupConLoss on MI355X. features: [4096, 2, 128] fp32; labels: [4096] int; out: 1 f32.
//
// R4 changes vs R3:
//  - k_possum DELETED. Label mask restored in k_negsum's epilogue (R1-style):
//    neg_sum is directly the masked sum. Kills 670K contended global atomics.
//  - k_loss: chunk-major transposed LDS layout (s_t[s][row], +1 pad) ->
//    consecutive-q lanes read consecutive 16B (conflict-free); p-row is a
//    wave-uniform broadcast. 182K bank conflicts -> ~0.
//
// ws layout: nf (2 MB) | neg_sum 8192 f32 | total 1 f32 | counts 100
//            | offsets 101 | classIdx 4096

#define BATCH 4096
#define NN    8192
#define DD    128
#define NCLS  100
#define MAXR  192
#define NB    64
#define NTILE (NB * (NB + 1) / 2)   // 2080
#define SCALE (1.0f / 0.07f)

typedef __attribute__((ext_vector_type(8))) short bf16x8;
typedef __attribute__((ext_vector_type(4))) float f32x4;

__device__ __forceinline__ unsigned short f2bf(float f) {
    unsigned u = __float_as_uint(f);
    u += 0x7FFF + ((u >> 16) & 1);
    return (unsigned short)(u >> 16);
}

__global__ void k_zero(float* p, int n) {
    int i = blockIdx.x * 256 + threadIdx.x;
    if (i < n) p[i] = 0.0f;
}

__global__ void k_normalize(const float* __restrict__ feat, unsigned short* __restrict__ nf) {
    int wave = threadIdx.x >> 6, lane = threadIdx.x & 63;
    int row = blockIdx.x * 4 + wave;
    int v = row >> 12, b = row & (BATCH - 1);
    const float2* src = (const float2*)(feat + ((size_t)b * 2 + v) * DD);
    float2 x = src[lane];
    float ss = x.x * x.x + x.y * x.y;
    #pragma unroll
    for (int m = 32; m >= 1; m >>= 1) ss += __shfl_xor(ss, m, 64);
    float inv = rsqrtf(ss);
    ushort2 o;
    o.x = f2bf(x.x * inv);
    o.y = f2bf(x.y * inv);
    ((ushort2*)(nf + (size_t)row * DD))[lane] = o;
}

__global__ __launch_bounds__(256) void k_bucket(const int* __restrict__ labels,
                                                int* __restrict__ counts,
                                                int* __restrict__ offsets,
                                                int* __restrict__ classIdx) {
    __shared__ int cnt[NCLS], off[NCLS], cur[NCLS];
    int tid = threadIdx.x;
    for (int c = tid; c < NCLS; c += 256) cnt[c] = 0;
    __syncthreads();
    for (int b = tid; b < BATCH; b += 256) atomicAdd(&cnt[labels[b]], 1);
    __syncthreads();
    if (tid == 0) {
        int a = 0;
        for (int c = 0; c < NCLS; ++c) { off[c] = a; a += cnt[c]; }
    }
    __syncthreads();
    for (int c = tid; c < NCLS; c += 256) {
        cur[c] = 0;
        counts[c] = cnt[c];
        offsets[c] = off[c];
    }
    if (tid == 0) offsets[NCLS] = BATCH;
    __syncthreads();
    for (int b = tid; b < BATCH; b += 256) {
        int l = labels[b];
        int p = atomicAdd(&cur[l], 1);
        classIdx[off[l] + p] = b;
    }
}

// ---- pass 1: neg_sum[i] = sum_j exp(logit_ij) [lab(i)!=lab(j)], symmetric ----
__global__ __launch_bounds__(256, 2) void k_negsum(
        const unsigned short* __restrict__ nf,
        const int* __restrict__ labels,
        float* __restrict__ neg_sum) {
    // 64 KB: 256 combined rows (128 A + 128 B) x 16 swizzled 16B chunks
    __shared__ __attribute__((aligned(16))) unsigned short smem[256 * 128];

    int t = blockIdx.x;
    float ft = (float)t;
    int bi = (int)((2.0f * NB + 1.0f - sqrtf((2.0f * NB + 1.0f) * (2.0f * NB + 1.0f) - 8.0f * ft)) * 0.5f);
    if (bi >= NB) bi = NB - 1;
    while (bi * (2 * NB + 1 - bi) / 2 > t) --bi;
    while ((bi + 1) * (2 * NB - bi) / 2 <= t) ++bi;
    int bj = bi + (t - bi * (2 * NB + 1 - bi) / 2);
    bool diag = (bi == bj);

    int tid = threadIdx.x;
    int wave = tid >> 6, lane = tid & 63;

    // stage: LDS slot (r, cS) holds global chunk (r, cS ^ (r&15))
    #pragma unroll
    for (int it = 0; it < 16; ++it) {
        int chunkIdx = (wave * 16 + it) * 64 + lane;
        int r = chunkIdx >> 4, cS = chunkIdx & 15;
        int cG = cS ^ (r & 15);
        int grow = (r < 128) ? (bi * 128 + r) : (bj * 128 + (r - 128));
        const unsigned short* g = nf + (size_t)grow * DD + cG * 8;
        unsigned short* l = smem + (size_t)(wave * 16 + it) * 512;
        __builtin_amdgcn_global_load_lds(
            (const __attribute__((address_space(1))) void*)g,
            (__attribute__((address_space(3))) void*)l, 16, 0, 0);
    }
    __syncthreads();

    int wr = wave >> 1, wc = wave & 1;
    int q = lane >> 4, nq = lane & 15;
    const char* sB = (const char*)smem;
    int rowBase = bi * 128 + wr * 64;
    int colBase = bj * 128 + wc * 64;

    bf16x8 aF[4][4];
    #pragma unroll
    for (int rs = 0; rs < 4; ++rs) {
        int rA = wr * 64 + rs * 16 + nq;
        #pragma unroll
        for (int s = 0; s < 4; ++s) {
            int slot = rA * 16 + ((s * 4 + q) ^ nq);
            aF[rs][s] = *(const bf16x8*)(sB + slot * 16);
        }
    }
    int rlab[4][4];
    #pragma unroll
    for (int rs = 0; rs < 4; ++rs)
        #pragma unroll
        for (int rr = 0; rr < 4; ++rr)
            rlab[rs][rr] = labels[(rowBase + rs * 16 + q * 4 + rr) & (BATCH - 1)];

    f32x4 acc[4][4];
    #pragma unroll
    for (int rs = 0; rs < 4; ++rs)
        #pragma unroll
        for (int cs = 0; cs < 4; ++cs) acc[rs][cs] = (f32x4){0.f, 0.f, 0.f, 0.f};
    #pragma unroll
    for (int s = 0; s < 4; ++s) {
        bf16x8 bF[4];
        #pragma unroll
        for (int cs = 0; cs < 4; ++cs) {
            int rB = 128 + wc * 64 + cs * 16 + nq;
            int slot = rB * 16 + ((s * 4 + q) ^ nq);
            bF[cs] = *(const bf16x8*)(sB + slot * 16);
        }
        #pragma unroll
        for (int rs = 0; rs < 4; ++rs)
            #pragma unroll
            for (int cs = 0; cs < 4; ++cs)
                acc[rs][cs] = __builtin_amdgcn_mfma_f32_16x16x32_bf16(
                    aF[rs][s], bF[cs], acc[rs][cs], 0, 0, 0);
    }

    float rowsum[4][4];
    #pragma unroll
    for (int rs = 0; rs < 4; ++rs)
        #pragma unroll
        for (int rr = 0; rr < 4; ++rr) rowsum[rs][rr] = 0.0f;

    // C/D layout: col = lane&15, row = (lane>>4)*4 + reg
    #pragma unroll
    for (int cs = 0; cs < 4; ++cs) {
        int col = colBase + cs * 16 + nq;
        int cl = labels[col & (BATCH - 1)];
        float colsum = 0.0f;
        #pragma unroll
        for (int rs = 0; rs < 4; ++rs)
            #pragma unroll
            for (int rr = 0; rr < 4; ++rr) {
                float e = __expf(acc[rs][cs][rr] * SCALE);
                float ev = (rlab[rs][rr] != cl) ? e : 0.0f;
                rowsum[rs][rr] += ev;
                colsum += ev;
            }
        if (!diag) {
            colsum += __shfl_xor(colsum, 16, 64);
            colsum += __shfl_xor(colsum, 32, 64);
            if (q == 0) atomicAdd(&neg_sum[col], colsum);
        }
    }
    #pragma unroll
    for (int rs = 0; rs < 4; ++rs)
        #pragma unroll
        for (int rr = 0; rr < 4; ++rr) {
            float vsum = rowsum[rs][rr];
            vsum += __shfl_xor(vsum, 1, 64);
            vsum += __shfl_xor(vsum, 2, 64);
            vsum += __shfl_xor(vsum, 4, 64);
            vsum += __shfl_xor(vsum, 8, 64);
            if (nq == 0) atomicAdd(&neg_sum[rowBase + rs * 16 + q * 4 + rr], vsum);
        }
}

// ---- pass 2: total += sum over pos pairs (p != q, same class) of
//              logit - log(neg_sum[row(q)] + exp(logit)) ----
#define LSLICE 8
__global__ __launch_bounds__(256) void k_loss(
        const unsigned short* __restrict__ nf,
        const int* __restrict__ counts, const int* __restrict__ offsets,
        const int* __restrict__ classIdx,
        const float* __restrict__ neg_sum,
        float* __restrict__ total) {
    __shared__ int s_rows[MAXR];
    __shared__ __attribute__((aligned(16))) uint4 s_t[16][MAXR + 1];  // chunk-major
    int c = blockIdx.x;
    int m = counts[c], off = offsets[c];
    int twoM = 2 * m; if (twoM > MAXR) twoM = MAXR;
    int tid = threadIdx.x;
    for (int r = tid; r < twoM; r += 256) {
        int b = classIdx[off + (r < m ? r : r - m)];
        s_rows[r] = (r < m) ? b : b + BATCH;
    }
    __syncthreads();
    for (int ch = tid; ch < twoM * 16; ch += 256) {
        int r = ch >> 4, s = ch & 15;   // consecutive tid -> consecutive global chunks
        s_t[s][r] = ((const uint4*)(nf + (size_t)s_rows[r] * DD))[s];
    }
    __syncthreads();

    float partial = 0.0f;
    unsigned P = (unsigned)twoM * (unsigned)twoM;
    for (unsigned t = blockIdx.y * 256 + tid; t < P; t += 256 * LSLICE) {
        unsigned p = t / (unsigned)twoM;
        unsigned qq = t - p * (unsigned)twoM;
        if (p == qq) continue;
        float dot = 0.0f;
        #pragma unroll
        for (int s = 0; s < 16; ++s) {
            uint4 ua = s_t[s][p];    // wave-uniform (broadcast)
            uint4 ub = s_t[s][qq];   // consecutive lanes -> consecutive 16B
            const unsigned* pa = (const unsigned*)&ua;
            const unsigned* pb = (const unsigned*)&ub;
            #pragma unroll
            for (int w = 0; w < 4; ++w) {
                float a0 = __uint_as_float(pa[w] << 16);
                float a1 = __uint_as_float(pa[w] & 0xFFFF0000u);
                float b0 = __uint_as_float(pb[w] << 16);
                float b1 = __uint_as_float(pb[w] & 0xFFFF0000u);
                dot = fmaf(a0, b0, dot);
                dot = fmaf(a1, b1, dot);
            }
        }
        float logit = dot * SCALE;
        float ns = neg_sum[s_rows[qq]];
        partial += logit - __logf(ns + __expf(logit));
    }
    #pragma unroll
    for (int mm = 32; mm >= 1; mm >>= 1) partial += __shfl_xor(partial, mm, 64);
    __shared__ float red[4];
    if ((tid & 63) == 0) red[tid >> 6] = partial;
    __syncthreads();
    if (tid == 0) atomicAdd(total, red[0] + red[1] + red[2] + red[3]);
}

__global__ void k_final(const float* __restrict__ total, float* __restrict__ out) {
    out[0] = -total[0] * (1.0f / (float)NN);
}

extern "C" void kernel_launch(void* const* d_in, const int* in_sizes, int n_in,
                              void* d_out, int out_size, void* d_ws, size_t ws_size,
                              hipStream_t stream) {
    const float* feat = (const float*)d_in[0];
    const int* labels = (const int*)d_in[1];
    unsigned short* nf = (unsigned short*)d_ws;
    float* neg_sum = (float*)((char*)d_ws + (size_t)NN * DD * sizeof(unsigned short));
    float* total   = neg_sum + NN;          // 1
    int* counts    = (int*)(total + 1);     // 100
    int* offsets   = counts + NCLS;         // 101
    int* classIdx  = offsets + NCLS + 1;    // 4096
    float* out = (float*)d_out;

    hipLaunchKernelGGL(k_zero, dim3((NN + 1 + 255) / 256), dim3(256), 0, stream, neg_sum, NN + 1);
    hipLaunchKernelGGL(k_normalize, dim3(NN / 4), dim3(256), 0, stream, feat, nf);
    hipLaunchKernelGGL(k_bucket, dim3(1), dim3(256), 0, stream, labels, counts, offsets, classIdx);
    hipLaunchKernelGGL(k_negsum, dim3(NTILE), dim3(256), 0, stream, nf, labels, neg_sum);
    hipLaunchKernelGGL(k_loss, dim3(NCLS, LSLICE), dim3(256), 0, stream,
                       nf, counts, offsets, classIdx, neg_sum, total);
    hipLaunchKernelGGL(k_final, dim3(1), dim3(1), 0, stream, total, out);
}